// Round 9
// baseline (322.492 us; speedup 1.0000x reference)
//
#include <hip/hip_runtime.h>
#include <float.h>
#include <math.h>

#define B_ 2
#define C_ 64
#define HW 64
#define M1 62
#define NP (M1*M1)      // 3844
#define WIN 30
#define KK 5
#define NSEL 16
#define HS 128

#define OUT_SCORE_SZ (B_*KK*HS*HS)       // 163840
#define OUT_IDX_OFF  (OUT_SCORE_SZ)
#define OUT_IDX_SZ   (B_*NP*KK)          // 38440
#define OUT_DIFF_OFF (OUT_IDX_OFF+OUT_IDX_SZ)
#define OUT_DIFF_SZ  (B_*KK*C_*HS*HS)    // 10485760

// ws layout in floats
#define WS_XNP 0                          // B_*NP = 7688 (pad 8192)
#define WS_YNP 8192
#define WS_TOP 16384                      // ints: B_*NP*16 = 123008
#define WS_SV  (16384+123008)             // 139392, B_*KK*NP = 38440 (pad 40960)
#define WS_DSUM (139392+40960)            // 180352, B_*KK*C_*NP = 2460160

typedef __attribute__((ext_vector_type(8))) short bf16x8;
typedef __attribute__((ext_vector_type(4))) float f32x4;

__device__ __forceinline__ unsigned short f2bf(float f) {
    union { float f; unsigned int u; } v; v.f = f;
    unsigned int r = (v.u + 0x7FFFu + ((v.u >> 16) & 1u)) >> 16;
    return (unsigned short)r;
}

// ---------------- K1: numpy-pairwise norms (bitwise np emulation) ------------
__global__ __launch_bounds__(256) void norm_np_kernel(const float* __restrict__ xe,
                                                      const float* __restrict__ ye,
                                                      float* __restrict__ xnp,
                                                      float* __restrict__ ynp) {
    __shared__ int tab[576];
    for (int t = threadIdx.x; t < 576; t += 256) {
        int c = t / 9, p = t - c * 9;
        tab[t] = c * (HW * HW) + (p / 3) * HW + (p % 3);
    }
    __syncthreads();

    int gid = blockIdx.x * 256 + threadIdx.x;
    if (gid >= 2 * B_ * NP * 8) return;
    int which = gid / (B_ * NP * 8);
    int rem = gid - which * (B_ * NP * 8);
    int patch = rem >> 3, leaf = rem & 7;
    int b = patch / NP, m = patch - b * NP;
    int r = m / M1, s = m - r * M1;
    const float* src = (which ? ye : xe) + (size_t)b * C_ * HW * HW + r * HW + s;

    int base = leaf * 72;
    float a8[8];
    #pragma unroll
    for (int i = 0; i < 8; i++) {
        float v = src[tab[base + i]];
        a8[i] = v * v;
    }
    for (int i0 = 8; i0 < 72; i0 += 8) {
        #pragma unroll
        for (int i = 0; i < 8; i++) {
            float v = src[tab[base + i0 + i]];
            a8[i] += v * v;
        }
    }
    float t = ((a8[0] + a8[1]) + (a8[2] + a8[3])) + ((a8[4] + a8[5]) + (a8[6] + a8[7]));
    t = t + __shfl_xor(t, 1, 8);
    t = t + __shfl_xor(t, 2, 8);
    t = t + __shfl_xor(t, 4, 8);
    if (leaf == 0) (which ? ynp : xnp)[patch] = t;
}

// ---------------- K2: MFMA prescreen + wave-level top-16 --------------------
#define UPR 35
#define UPC 42       // pixel cols slots (40 staged + 2 pad): a-stride 840 words = 8 mod 32
#define CSTR 40      // bf16 channel stride (32 ch + 8 pad): 80B, 16B-aligned
#define YSTR 584     // 576 + 8 pad

#define XS_BYTES (UPR*UPC*CSTR*2)          // 117600
#define YS_OFFB  XS_BYTES                  // 117600
#define XN_OFFB  (YS_OFFB + 16*YSTR*2)     // 136288
#define SM_BYTES (XN_OFFB + 1089*4 + 16)   // 140660

__global__ __launch_bounds__(1024) void gemm_select_kernel(const float* __restrict__ xe,
                                                           const float* __restrict__ ye,
                                                           const float* __restrict__ xnp,
                                                           int* __restrict__ top_ws) {
    __shared__ __align__(16) unsigned char smem[SM_BYTES];
    short* xsS = (short*)smem;
    unsigned int* xsW = (unsigned int*)smem;
    short* ysS = (short*)(smem + YS_OFFB);
    float* xnL = (float*)(smem + XN_OFFB);
    float* Dl  = (float*)smem;            // reuses xs region after MFMA

    const int bid = blockIdx.x;
    const int b  = bid >> 8;
    const int t  = bid & 255;
    const int r0 = (t >> 4) * 4;
    const int s0 = (t & 15) * 4;
    const int u0r = min(max(r0 - 15, 0), 32);
    const int u0c = min(max(s0 - 15, 0), 32);
    const int g0c = min(u0c & ~3, 24);    // aligned staged col origin
    const int cofs = u0c - g0c;
    const int tid = threadIdx.x;
    const int l   = tid & 63;
    const int wid = tid >> 6;             // 0..15
    const int lq  = l & 15;
    const int kg  = l >> 4;               // 0..3

    // stage y patches (bf16, e = p*64+c) and xn for the candidate union
    for (int i = tid; i < 16 * 576; i += 1024) {
        int q = i / 576, e = i - q * 576;
        int p = e >> 6, c = e & 63;
        int rq = min(r0 + (q >> 2), 61), sq = min(s0 + (q & 3), 61);
        float v = ye[((b * C_ + c) * HW + rq + p / 3) * HW + sq + p % 3];
        ysS[q * YSTR + e] = (short)f2bf(v);
    }
    for (int i = tid; i < 1089; i += 1024) {
        int cr = i / 33, cc = i - cr * 33;
        int nr = min(u0r + cr, 61), nc = min(u0c + cc, 61);
        xnL[i] = xnp[b * NP + nr * M1 + nc];
    }

    f32x4 acc[5];
    #pragma unroll
    for (int i = 0; i < 5; i++) acc[i] = (f32x4){0.f, 0.f, 0.f, 0.f};

    int prb[5], pcb[5];
    #pragma unroll
    for (int i = 0; i < 5; i++) {
        int ci = (wid * 5 + i) * 16 + lq;  // 0..1279
        int cis = min(ci, 1088);           // clamp phantoms in-bounds
        int cr = cis / 33;
        prb[i] = cr;
        pcb[i] = cis - cr * 33 + cofs;
    }

    for (int ch = 0; ch < 2; ch++) {
        __syncthreads();
        for (int u = tid; u < 16 * 35; u += 1024) {
            int cp = u & 15, a = u >> 4;
            int c0 = ch * 32 + cp * 2;
            int gr = min(u0r + a, 63);
            const float4* pa = (const float4*)(xe + ((size_t)(b * C_ + c0) * HW + gr) * HW + g0c);
            const float4* pb = (const float4*)(xe + ((size_t)(b * C_ + c0 + 1) * HW + gr) * HW + g0c);
            #pragma unroll
            for (int blk = 0; blk < 10; blk++) {
                float4 va = pa[blk], vb = pb[blk];
                int w0 = (a * UPC + blk * 4) * (CSTR / 2) + cp;  // u32 word index
                xsW[w0                ] = (unsigned)f2bf(va.x) | ((unsigned)f2bf(vb.x) << 16);
                xsW[w0 +     CSTR / 2 ] = (unsigned)f2bf(va.y) | ((unsigned)f2bf(vb.y) << 16);
                xsW[w0 +     CSTR     ] = (unsigned)f2bf(va.z) | ((unsigned)f2bf(vb.z) << 16);
                xsW[w0 + 3 * CSTR / 2 ] = (unsigned)f2bf(va.w) | ((unsigned)f2bf(vb.w) << 16);
            }
        }
        __syncthreads();
        #pragma unroll
        for (int p = 0; p < 9; p++) {
            const int pi = p / 3, pj = p % 3;
            bf16x8 af = *(const bf16x8*)(ysS + lq * YSTR + p * 64 + ch * 32 + kg * 8);
            #pragma unroll
            for (int i = 0; i < 5; i++) {
                const short* bp = xsS + ((prb[i] + pi) * UPC + (pcb[i] + pj)) * CSTR + kg * 8;
                bf16x8 bf = *(const bf16x8*)bp;
                acc[i] = __builtin_amdgcn_mfma_f32_16x16x32_bf16(af, bf, acc[i], 0, 0, 0);
            }
        }
    }

    __syncthreads();
    #pragma unroll
    for (int i = 0; i < 5; i++) {
        int ci = (wid * 5 + i) * 16 + lq;
        if (ci < 1089) {
            float xnv = xnL[ci];
            #pragma unroll
            for (int j = 0; j < 4; j++) {
                Dl[(kg * 4 + j) * 1089 + ci] = xnv - 2.0f * acc[i][j];
            }
        }
    }
    __syncthreads();

    // wave-level top-16: one query per wave
    {
        int q = wid;
        int rq = r0 + (q >> 2), sq = s0 + (q & 3);
        if (rq <= 61 && sq <= 61) {
            int siq = min(max(rq - 15, 0), 32);
            int sjq = min(max(sq - 15, 0), 32);
            int ro = siq - u0r, co = sjq - u0c;
            float kv[15]; int wv[15];
            #pragma unroll
            for (int kk = 0; kk < 15; kk++) {
                int w = kk * 64 + l;
                if (w < 900) {
                    int wi = w / 30, wj = w - wi * 30;
                    kv[kk] = Dl[q * 1089 + (ro + wi) * 33 + (co + wj)];
                    wv[kk] = w;
                } else { kv[kk] = FLT_MAX; wv[kk] = 1 << 30; }
            }
            int obase = (b * NP + rq * M1 + sq) * NSEL;
            for (int it = 0; it < NSEL; it++) {
                float bk = FLT_MAX; int bw = 1 << 30;
                #pragma unroll
                for (int kk = 0; kk < 15; kk++)
                    if (kv[kk] < bk || (kv[kk] == bk && wv[kk] < bw)) { bk = kv[kk]; bw = wv[kk]; }
                #pragma unroll
                for (int off = 32; off >= 1; off >>= 1) {
                    float ok = __shfl_xor(bk, off);
                    int   ow = __shfl_xor(bw, off);
                    if (ok < bk || (ok == bk && ow < bw)) { bk = ok; bw = ow; }
                }
                #pragma unroll
                for (int kk = 0; kk < 15; kk++)
                    if (wv[kk] == bw) kv[kk] = FLT_MAX;
                if (l == 0) {
                    int wi = bw / 30, wj = bw - wi * 30;
                    top_ws[obase + it] = (siq + wi) * M1 + (sjq + wj);
                }
            }
        }
    }
}

// ---------------- K3: bitwise np-f32 emulation + outputs --------------------
// LDS-staged candidates: all 16 survivor patches are cooperatively loaded into
// LDS (pipelined, no dependent chains), then the bit-exact serial FMA chain and
// the dsum L1 sums read from LDS. Float op order unchanged -> identical keys.
#define XCSTR 584   // candidate patch stride (576 + 8): 584%32=8 -> 2-way banks

__global__ __launch_bounds__(256) void emu_kernel(const float* __restrict__ xe,
                                                  const float* __restrict__ ye,
                                                  const float* __restrict__ xnp,
                                                  const float* __restrict__ ynp,
                                                  const int* __restrict__ top_ws,
                                                  float* __restrict__ out_idx,
                                                  float* __restrict__ sv_ws,
                                                  float* __restrict__ dsum_ws) {
    __shared__ float ysE[576];
    __shared__ int tab[576];
    __shared__ float xc[NSEL * XCSTR];
    __shared__ int topWs[NSEL];
    __shared__ float keyEmu[NSEL];
    __shared__ float selKey[KK];
    __shared__ int   selN[KK];
    __shared__ int   selI[KK];

    // XCD-affine swizzle: consecutive m -> same XCD (blockIdx%8 assumed XCD id);
    // merges dsum/sv cache lines within one L2. Bijective: 7688 = 8*961.
    const int bid0 = blockIdx.x;
    const int bid = (bid0 & 7) * (B_ * NP / 8) + (bid0 >> 3);
    const int b = bid / NP, m = bid - b * NP;
    const int r = m / M1, s = m - r * M1;
    const int tid = threadIdx.x;
    const float* xb = xe + (size_t)b * C_ * HW * HW;
    const float* yb = ye + (size_t)b * C_ * HW * HW + r * HW + s;

    for (int t = tid; t < 576; t += 256) {
        int c = t / 9, p = t - c * 9;
        tab[t] = c * (HW * HW) + (p / 3) * HW + (p % 3);
    }
    if (tid < NSEL) topWs[tid] = top_ws[bid * NSEL + tid];
    __syncthreads();

    // stage y patch (e-order) and all 16 candidate patches into LDS
    for (int t = tid; t < 576; t += 256) ysE[t] = yb[tab[t]];
    for (int i = tid; i < NSEL * 576; i += 256) {
        int cand = i / 576, e = i - cand * 576;
        int n = topWs[cand];
        int px = n / M1, py = n - px * M1;
        xc[cand * XCSTR + e] = xb[px * HW + py + tab[e]];
    }
    __syncthreads();

    {   // einsum E emulation: AVX512 single-vaccum nested-FMA, lane j owns e≡j (mod 16)
        const int cand = tid >> 4, j = tid & 15;
        const float* xcp = xc + cand * XCSTR;
        float acc = 0.f;
        #pragma unroll
        for (int t = 0; t < 36; t++) {
            int e = t * 16 + j;
            acc = fmaf(ysE[e], xcp[e], acc);
        }
        float E = acc;
        E = E + __shfl_xor(E, 8, 16);
        E = E + __shfl_xor(E, 4, 16);
        E = E + __shfl_xor(E, 2, 16);
        E = E + __shfl_xor(E, 1, 16);
        if (j == 0) {
            float t0 = -2.0f * E;
            float k1 = t0 + ynp[b * NP + m];
            float k2 = k1 + xnp[b * NP + topWs[cand]];
            keyEmu[cand] = k2 + 1e-5f;
        }
    }
    __syncthreads();

    if (tid == 0) {
        float d[NSEL]; int w[NSEL]; int ix[NSEL];
        for (int i = 0; i < NSEL; i++) { d[i] = keyEmu[i]; w[i] = topWs[i]; ix[i] = i; }
        for (int a = 1; a < NSEL; a++) {
            float dv = d[a]; int wv2 = w[a]; int iv = ix[a]; int p = a - 1;
            while (p >= 0 && (d[p] > dv || (d[p] == dv && w[p] > wv2))) {
                d[p + 1] = d[p]; w[p + 1] = w[p]; ix[p + 1] = ix[p]; p--;
            }
            d[p + 1] = dv; w[p + 1] = wv2; ix[p + 1] = iv;
        }
        for (int i = 0; i < KK; i++) { selKey[i] = d[i]; selN[i] = w[i]; selI[i] = ix[i]; }
    }
    __syncthreads();

    if (tid < KK) {
        out_idx[(b * NP + m) * KK + tid] = (float)selN[tid];
        float s10 = selKey[tid] / 10.0f;
        double sv = exp(-(double)s10);
        sv_ws[(b * KK + tid) * NP + m] = (float)sv;
    }

    // per-channel L1 sums for the 5 winners, entirely from LDS
    for (int pair = tid; pair < KK * C_; pair += 256) {
        int k = pair >> 6, c = pair & 63;
        const float* xcp = xc + selI[k] * XCSTR + c * 9;
        const float* ycp = ysE + c * 9;
        float a = 0.f;
        #pragma unroll
        for (int p = 0; p < 9; p++) {
            a += fabsf(ycp[p] - xcp[p]);
        }
        dsum_ws[((b * KK + k) * C_ + c) * NP + m] = a;
    }
}

// ---------------- overlap-add image kernels ---------------------------------
__device__ __forceinline__ void oa_range(int y, int& r0, int& r1) {
    r0 = (y >= 5) ? ((y - 4) >> 1) : 0;
    r1 = min(M1 - 1, y >> 1);
}

__global__ __launch_bounds__(256) void score_img_kernel(const float* __restrict__ sv_ws,
                                                        float* __restrict__ out) {
    int idx = blockIdx.x * 256 + threadIdx.x;
    if (idx >= OUT_SCORE_SZ) return;
    int x = idx & 127, y = (idx >> 7) & 127;
    int bk = idx >> 14;
    int r0, r1, s0, s1;
    oa_range(y, r0, r1);
    oa_range(x, s0, s1);
    const float* base = sv_ws + bk * NP;
    float acc = 0.f;
    for (int rr = r0; rr <= r1; rr++)
        for (int ss = s0; ss <= s1; ss++)
            acc += base[rr * M1 + ss];
    out[idx] = acc;
}

__global__ __launch_bounds__(256) void diff_img_kernel(const float* __restrict__ dsum_ws,
                                                       float* __restrict__ out) {
    int idx = blockIdx.x * 256 + threadIdx.x;
    if (idx >= OUT_DIFF_SZ) return;
    int x = idx & 127, y = (idx >> 7) & 127;
    int bkc = idx >> 14;
    int r0, r1, s0, s1;
    oa_range(y, r0, r1);
    oa_range(x, s0, s1);
    const float* base = dsum_ws + bkc * NP;
    float acc = 0.f;
    for (int rr = r0; rr <= r1; rr++)
        for (int ss = s0; ss <= s1; ss++)
            acc += base[rr * M1 + ss];
    out[idx] = acc;
}

extern "C" void kernel_launch(void* const* d_in, const int* in_sizes, int n_in,
                              void* d_out, int out_size, void* d_ws, size_t ws_size,
                              hipStream_t stream) {
    const float* xe = (const float*)d_in[0];
    const float* ye = (const float*)d_in[1];
    float* out = (float*)d_out;
    float* ws = (float*)d_ws;

    float* xnp = ws + WS_XNP;
    float* ynp = ws + WS_YNP;
    int*   topw = (int*)(ws + WS_TOP);
    float* sv_ws = ws + WS_SV;
    float* dsum_ws = ws + WS_DSUM;

    norm_np_kernel<<<(2 * B_ * NP * 8 + 255) / 256, 256, 0, stream>>>(xe, ye, xnp, ynp);
    gemm_select_kernel<<<2 * 256, 1024, 0, stream>>>(xe, ye, xnp, topw);
    emu_kernel<<<B_ * NP, 256, 0, stream>>>(xe, ye, xnp, ynp, topw,
                                            out + OUT_IDX_OFF, sv_ws, dsum_ws);
    score_img_kernel<<<OUT_SCORE_SZ / 256, 256, 0, stream>>>(sv_ws, out);
    diff_img_kernel<<<OUT_DIFF_SZ / 256, 256, 0, stream>>>(dsum_ws, out + OUT_DIFF_OFF);
}

// Round 10
// 243.241 us; speedup vs baseline: 1.3258x; 1.3258x over previous
//
#include <hip/hip_runtime.h>
#include <float.h>
#include <math.h>

#define B_ 2
#define C_ 64
#define HW 64
#define M1 62
#define NP (M1*M1)      // 3844
#define WIN 30
#define KK 5
#define NSEL 16
#define HS 128

#define OUT_SCORE_SZ (B_*KK*HS*HS)       // 163840
#define OUT_IDX_OFF  (OUT_SCORE_SZ)
#define OUT_IDX_SZ   (B_*NP*KK)          // 38440
#define OUT_DIFF_OFF (OUT_IDX_OFF+OUT_IDX_SZ)
#define OUT_DIFF_SZ  (B_*KK*C_*HS*HS)    // 10485760

// ws layout in floats
#define WS_XNP 0                          // B_*NP = 7688 (pad 8192)
#define WS_YNP 8192
#define WS_TOP 16384                      // ints: B_*NP*16 = 123008
#define WS_SV  (16384+123008)             // 139392, B_*KK*NP = 38440 (pad 40960)
#define WS_DSUM (139392+40960)            // 180352, B_*KK*C_*NP = 2460160
#define WS_XPM  (180352+2460160)          // 2640512
#define XPM_F   (B_*NP*576)               // 4428288 floats
#define WS_YPM  (WS_XPM + XPM_F)          // 7068800
#define WS_NEED_BYTES ((size_t)(WS_YPM + XPM_F) * 4)   // ~46 MB

typedef __attribute__((ext_vector_type(8))) short bf16x8;
typedef __attribute__((ext_vector_type(4))) float f32x4;

__device__ __forceinline__ unsigned short f2bf(float f) {
    union { float f; unsigned int u; } v; v.f = f;
    unsigned int r = (v.u + 0x7FFFu + ((v.u >> 16) & 1u)) >> 16;
    return (unsigned short)r;
}

// ---------------- K0: im2patch (patch-major copies, e = c*9+p order) --------
__global__ __launch_bounds__(256) void im2patch_kernel(const float* __restrict__ xe,
                                                       const float* __restrict__ ye,
                                                       float* __restrict__ xpm,
                                                       float* __restrict__ ypm) {
    __shared__ float rows[3 * 64 * 64];   // [c][rr][col] = c*192 + rr*64 + col
    __shared__ int tabL[576];
    const int tid = threadIdx.x;
    const int bid = blockIdx.x;           // src*B_*62 + b*62 + r
    const int srcI = bid / (B_ * 62);
    const int rem = bid - srcI * (B_ * 62);
    const int b = rem / M1, r = rem - b * M1;
    const float* src = (srcI ? ye : xe) + (size_t)b * C_ * HW * HW;
    float* dst = (srcI ? ypm : xpm) + (size_t)(b * NP + r * M1) * 576;

    for (int t = tid; t < 576; t += 256) {
        int c = t / 9, p = t - c * 9;
        tabL[t] = c * 192 + (p / 3) * 64 + (p % 3);
    }
    for (int i = tid; i < 64 * 192; i += 256) {
        rows[i] = src[(i / 192) * (HW * HW) + r * HW + (i % 192)];
    }
    __syncthreads();

    for (int s = 0; s < M1; s++) {
        float* d = dst + s * 576;
        for (int e = tid; e < 576; e += 256) d[e] = rows[tabL[e] + s];
    }
}

// ---------------- K1: numpy-pairwise norms (bitwise np emulation) ------------
__global__ __launch_bounds__(256) void norm_np_kernel(const float* __restrict__ xe,
                                                      const float* __restrict__ ye,
                                                      float* __restrict__ xnp,
                                                      float* __restrict__ ynp) {
    __shared__ int tab[576];
    for (int t = threadIdx.x; t < 576; t += 256) {
        int c = t / 9, p = t - c * 9;
        tab[t] = c * (HW * HW) + (p / 3) * HW + (p % 3);
    }
    __syncthreads();

    int gid = blockIdx.x * 256 + threadIdx.x;
    if (gid >= 2 * B_ * NP * 8) return;
    int which = gid / (B_ * NP * 8);
    int rem = gid - which * (B_ * NP * 8);
    int patch = rem >> 3, leaf = rem & 7;
    int b = patch / NP, m = patch - b * NP;
    int r = m / M1, s = m - r * M1;
    const float* src = (which ? ye : xe) + (size_t)b * C_ * HW * HW + r * HW + s;

    int base = leaf * 72;
    float a8[8];
    #pragma unroll
    for (int i = 0; i < 8; i++) {
        float v = src[tab[base + i]];
        a8[i] = v * v;
    }
    for (int i0 = 8; i0 < 72; i0 += 8) {
        #pragma unroll
        for (int i = 0; i < 8; i++) {
            float v = src[tab[base + i0 + i]];
            a8[i] += v * v;
        }
    }
    float t = ((a8[0] + a8[1]) + (a8[2] + a8[3])) + ((a8[4] + a8[5]) + (a8[6] + a8[7]));
    t = t + __shfl_xor(t, 1, 8);
    t = t + __shfl_xor(t, 2, 8);
    t = t + __shfl_xor(t, 4, 8);
    if (leaf == 0) (which ? ynp : xnp)[patch] = t;
}

// ---------------- K2: MFMA prescreen + wave-level top-16 --------------------
#define UPR 35
#define UPC 42
#define CSTR 40
#define YSTR 584

#define XS_BYTES (UPR*UPC*CSTR*2)          // 117600
#define YS_OFFB  XS_BYTES
#define XN_OFFB  (YS_OFFB + 16*YSTR*2)
#define SM_BYTES (XN_OFFB + 1089*4 + 16)

__global__ __launch_bounds__(1024) void gemm_select_kernel(const float* __restrict__ xe,
                                                           const float* __restrict__ ye,
                                                           const float* __restrict__ xnp,
                                                           int* __restrict__ top_ws) {
    __shared__ __align__(16) unsigned char smem[SM_BYTES];
    short* xsS = (short*)smem;
    unsigned int* xsW = (unsigned int*)smem;
    short* ysS = (short*)(smem + YS_OFFB);
    float* xnL = (float*)(smem + XN_OFFB);
    float* Dl  = (float*)smem;

    const int bid = blockIdx.x;
    const int b  = bid >> 8;
    const int t  = bid & 255;
    const int r0 = (t >> 4) * 4;
    const int s0 = (t & 15) * 4;
    const int u0r = min(max(r0 - 15, 0), 32);
    const int u0c = min(max(s0 - 15, 0), 32);
    const int g0c = min(u0c & ~3, 24);
    const int cofs = u0c - g0c;
    const int tid = threadIdx.x;
    const int l   = tid & 63;
    const int wid = tid >> 6;
    const int lq  = l & 15;
    const int kg  = l >> 4;

    for (int i = tid; i < 16 * 576; i += 1024) {
        int q = i / 576, e = i - q * 576;
        int p = e >> 6, c = e & 63;
        int rq = min(r0 + (q >> 2), 61), sq = min(s0 + (q & 3), 61);
        float v = ye[((b * C_ + c) * HW + rq + p / 3) * HW + sq + p % 3];
        ysS[q * YSTR + e] = (short)f2bf(v);
    }
    for (int i = tid; i < 1089; i += 1024) {
        int cr = i / 33, cc = i - cr * 33;
        int nr = min(u0r + cr, 61), nc = min(u0c + cc, 61);
        xnL[i] = xnp[b * NP + nr * M1 + nc];
    }

    f32x4 acc[5];
    #pragma unroll
    for (int i = 0; i < 5; i++) acc[i] = (f32x4){0.f, 0.f, 0.f, 0.f};

    int prb[5], pcb[5];
    #pragma unroll
    for (int i = 0; i < 5; i++) {
        int ci = (wid * 5 + i) * 16 + lq;
        int cis = min(ci, 1088);
        int cr = cis / 33;
        prb[i] = cr;
        pcb[i] = cis - cr * 33 + cofs;
    }

    for (int ch = 0; ch < 2; ch++) {
        __syncthreads();
        for (int u = tid; u < 16 * 35; u += 1024) {
            int cp = u & 15, a = u >> 4;
            int c0 = ch * 32 + cp * 2;
            int gr = min(u0r + a, 63);
            const float4* pa = (const float4*)(xe + ((size_t)(b * C_ + c0) * HW + gr) * HW + g0c);
            const float4* pb = (const float4*)(xe + ((size_t)(b * C_ + c0 + 1) * HW + gr) * HW + g0c);
            #pragma unroll
            for (int blk = 0; blk < 10; blk++) {
                float4 va = pa[blk], vb = pb[blk];
                int w0 = (a * UPC + blk * 4) * (CSTR / 2) + cp;
                xsW[w0                ] = (unsigned)f2bf(va.x) | ((unsigned)f2bf(vb.x) << 16);
                xsW[w0 +     CSTR / 2 ] = (unsigned)f2bf(va.y) | ((unsigned)f2bf(vb.y) << 16);
                xsW[w0 +     CSTR     ] = (unsigned)f2bf(va.z) | ((unsigned)f2bf(vb.z) << 16);
                xsW[w0 + 3 * CSTR / 2 ] = (unsigned)f2bf(va.w) | ((unsigned)f2bf(vb.w) << 16);
            }
        }
        __syncthreads();
        #pragma unroll
        for (int p = 0; p < 9; p++) {
            const int pi = p / 3, pj = p % 3;
            bf16x8 af = *(const bf16x8*)(ysS + lq * YSTR + p * 64 + ch * 32 + kg * 8);
            #pragma unroll
            for (int i = 0; i < 5; i++) {
                const short* bp = xsS + ((prb[i] + pi) * UPC + (pcb[i] + pj)) * CSTR + kg * 8;
                bf16x8 bf = *(const bf16x8*)bp;
                acc[i] = __builtin_amdgcn_mfma_f32_16x16x32_bf16(af, bf, acc[i], 0, 0, 0);
            }
        }
    }

    __syncthreads();
    #pragma unroll
    for (int i = 0; i < 5; i++) {
        int ci = (wid * 5 + i) * 16 + lq;
        if (ci < 1089) {
            float xnv = xnL[ci];
            #pragma unroll
            for (int j = 0; j < 4; j++) {
                Dl[(kg * 4 + j) * 1089 + ci] = xnv - 2.0f * acc[i][j];
            }
        }
    }
    __syncthreads();

    {
        int q = wid;
        int rq = r0 + (q >> 2), sq = s0 + (q & 3);
        if (rq <= 61 && sq <= 61) {
            int siq = min(max(rq - 15, 0), 32);
            int sjq = min(max(sq - 15, 0), 32);
            int ro = siq - u0r, co = sjq - u0c;
            float kv[15]; int wv[15];
            #pragma unroll
            for (int kk = 0; kk < 15; kk++) {
                int w = kk * 64 + l;
                if (w < 900) {
                    int wi = w / 30, wj = w - wi * 30;
                    kv[kk] = Dl[q * 1089 + (ro + wi) * 33 + (co + wj)];
                    wv[kk] = w;
                } else { kv[kk] = FLT_MAX; wv[kk] = 1 << 30; }
            }
            int obase = (b * NP + rq * M1 + sq) * NSEL;
            for (int it = 0; it < NSEL; it++) {
                float bk = FLT_MAX; int bw = 1 << 30;
                #pragma unroll
                for (int kk = 0; kk < 15; kk++)
                    if (kv[kk] < bk || (kv[kk] == bk && wv[kk] < bw)) { bk = kv[kk]; bw = wv[kk]; }
                #pragma unroll
                for (int off = 32; off >= 1; off >>= 1) {
                    float ok = __shfl_xor(bk, off);
                    int   ow = __shfl_xor(bw, off);
                    if (ok < bk || (ok == bk && ow < bw)) { bk = ok; bw = ow; }
                }
                #pragma unroll
                for (int kk = 0; kk < 15; kk++)
                    if (wv[kk] == bw) kv[kk] = FLT_MAX;
                if (l == 0) {
                    int wi = bw / 30, wj = bw - wi * 30;
                    top_ws[obase + it] = (siq + wi) * M1 + (sjq + wj);
                }
            }
        }
    }
}

// ---------------- K3a: emu from patch-major buffers (dense reads) -----------
__global__ __launch_bounds__(256) void emu_pm_kernel(const float* __restrict__ xpm,
                                                     const float* __restrict__ ypm,
                                                     const float* __restrict__ xnp,
                                                     const float* __restrict__ ynp,
                                                     const int* __restrict__ top_ws,
                                                     float* __restrict__ out_idx,
                                                     float* __restrict__ sv_ws,
                                                     float* __restrict__ dsum_ws) {
    __shared__ float ysE[576];
    __shared__ int topWs[NSEL];
    __shared__ float keyEmu[NSEL];
    __shared__ float selKey[KK];
    __shared__ int   selN[KK];

    const int bid0 = blockIdx.x;
    const int bid = (bid0 & 7) * (B_ * NP / 8) + (bid0 >> 3);  // XCD-affine
    const int b = bid / NP, m = bid - b * NP;
    const int tid = threadIdx.x;
    const float* ybase = ypm + (size_t)(b * NP + m) * 576;

    for (int t = tid; t < 576; t += 256) ysE[t] = ybase[t];
    if (tid < NSEL) topWs[tid] = top_ws[bid * NSEL + tid];
    __syncthreads();

    {   // einsum emulation: dense coalesced reads from xpm, same FMA order
        const int cand = tid >> 4, j = tid & 15;
        const float* xp = xpm + (size_t)(b * NP + topWs[cand]) * 576;
        float acc = 0.f;
        #pragma unroll
        for (int t = 0; t < 36; t++) {
            int e = t * 16 + j;
            acc = fmaf(ysE[e], xp[e], acc);
        }
        float E = acc;
        E = E + __shfl_xor(E, 8, 16);
        E = E + __shfl_xor(E, 4, 16);
        E = E + __shfl_xor(E, 2, 16);
        E = E + __shfl_xor(E, 1, 16);
        if (j == 0) {
            float t0 = -2.0f * E;
            float k1 = t0 + ynp[b * NP + m];
            float k2 = k1 + xnp[b * NP + topWs[cand]];
            keyEmu[cand] = k2 + 1e-5f;
        }
    }
    __syncthreads();

    if (tid == 0) {
        float d[NSEL]; int w[NSEL];
        for (int i = 0; i < NSEL; i++) { d[i] = keyEmu[i]; w[i] = topWs[i]; }
        for (int a = 1; a < NSEL; a++) {
            float dv = d[a]; int wv2 = w[a]; int p = a - 1;
            while (p >= 0 && (d[p] > dv || (d[p] == dv && w[p] > wv2))) {
                d[p + 1] = d[p]; w[p + 1] = w[p]; p--;
            }
            d[p + 1] = dv; w[p + 1] = wv2;
        }
        for (int i = 0; i < KK; i++) { selKey[i] = d[i]; selN[i] = w[i]; }
    }
    __syncthreads();

    if (tid < KK) {
        out_idx[(b * NP + m) * KK + tid] = (float)selN[tid];
        float s10 = selKey[tid] / 10.0f;
        double sv = exp(-(double)s10);
        sv_ws[(b * KK + tid) * NP + m] = (float)sv;
    }

    for (int pair = tid; pair < KK * C_; pair += 256) {
        int k = pair >> 6, c = pair & 63;
        const float* xrow = xpm + (size_t)(b * NP + selN[k]) * 576 + c * 9;
        const float* yrow = ysE + c * 9;
        float a = 0.f;
        #pragma unroll
        for (int p = 0; p < 9; p++) a += fabsf(yrow[p] - xrow[p]);
        dsum_ws[((b * KK + k) * C_ + c) * NP + m] = a;
    }
}

// ---------------- K3b: fallback emu (round-9, scattered) --------------------
#define XCSTR 584

__global__ __launch_bounds__(256) void emu_fallback_kernel(const float* __restrict__ xe,
                                                           const float* __restrict__ ye,
                                                           const float* __restrict__ xnp,
                                                           const float* __restrict__ ynp,
                                                           const int* __restrict__ top_ws,
                                                           float* __restrict__ out_idx,
                                                           float* __restrict__ sv_ws,
                                                           float* __restrict__ dsum_ws) {
    __shared__ float ysE[576];
    __shared__ int tab[576];
    __shared__ float xc[NSEL * XCSTR];
    __shared__ int topWs[NSEL];
    __shared__ float keyEmu[NSEL];
    __shared__ float selKey[KK];
    __shared__ int   selN[KK];
    __shared__ int   selI[KK];

    const int bid0 = blockIdx.x;
    const int bid = (bid0 & 7) * (B_ * NP / 8) + (bid0 >> 3);
    const int b = bid / NP, m = bid - b * NP;
    const int r = m / M1, s = m - r * M1;
    const int tid = threadIdx.x;
    const float* xb = xe + (size_t)b * C_ * HW * HW;
    const float* yb = ye + (size_t)b * C_ * HW * HW + r * HW + s;

    for (int t = tid; t < 576; t += 256) {
        int c = t / 9, p = t - c * 9;
        tab[t] = c * (HW * HW) + (p / 3) * HW + (p % 3);
    }
    if (tid < NSEL) topWs[tid] = top_ws[bid * NSEL + tid];
    __syncthreads();

    for (int t = tid; t < 576; t += 256) ysE[t] = yb[tab[t]];
    for (int i = tid; i < NSEL * 576; i += 256) {
        int cand = i / 576, e = i - cand * 576;
        int n = topWs[cand];
        int px = n / M1, py = n - px * M1;
        xc[cand * XCSTR + e] = xb[px * HW + py + tab[e]];
    }
    __syncthreads();

    {
        const int cand = tid >> 4, j = tid & 15;
        const float* xcp = xc + cand * XCSTR;
        float acc = 0.f;
        #pragma unroll
        for (int t = 0; t < 36; t++) {
            int e = t * 16 + j;
            acc = fmaf(ysE[e], xcp[e], acc);
        }
        float E = acc;
        E = E + __shfl_xor(E, 8, 16);
        E = E + __shfl_xor(E, 4, 16);
        E = E + __shfl_xor(E, 2, 16);
        E = E + __shfl_xor(E, 1, 16);
        if (j == 0) {
            float t0 = -2.0f * E;
            float k1 = t0 + ynp[b * NP + m];
            float k2 = k1 + xnp[b * NP + topWs[cand]];
            keyEmu[cand] = k2 + 1e-5f;
        }
    }
    __syncthreads();

    if (tid == 0) {
        float d[NSEL]; int w[NSEL]; int ix[NSEL];
        for (int i = 0; i < NSEL; i++) { d[i] = keyEmu[i]; w[i] = topWs[i]; ix[i] = i; }
        for (int a = 1; a < NSEL; a++) {
            float dv = d[a]; int wv2 = w[a]; int iv = ix[a]; int p = a - 1;
            while (p >= 0 && (d[p] > dv || (d[p] == dv && w[p] > wv2))) {
                d[p + 1] = d[p]; w[p + 1] = w[p]; ix[p + 1] = ix[p]; p--;
            }
            d[p + 1] = dv; w[p + 1] = wv2; ix[p + 1] = iv;
        }
        for (int i = 0; i < KK; i++) { selKey[i] = d[i]; selN[i] = w[i]; selI[i] = ix[i]; }
    }
    __syncthreads();

    if (tid < KK) {
        out_idx[(b * NP + m) * KK + tid] = (float)selN[tid];
        float s10 = selKey[tid] / 10.0f;
        double sv = exp(-(double)s10);
        sv_ws[(b * KK + tid) * NP + m] = (float)sv;
    }

    for (int pair = tid; pair < KK * C_; pair += 256) {
        int k = pair >> 6, c = pair & 63;
        const float* xcp = xc + selI[k] * XCSTR + c * 9;
        const float* ycp = ysE + c * 9;
        float a = 0.f;
        #pragma unroll
        for (int p = 0; p < 9; p++) a += fabsf(ycp[p] - xcp[p]);
        dsum_ws[((b * KK + k) * C_ + c) * NP + m] = a;
    }
}

// ---------------- overlap-add image kernels ---------------------------------
__device__ __forceinline__ void oa_range(int y, int& r0, int& r1) {
    r0 = (y >= 5) ? ((y - 4) >> 1) : 0;
    r1 = min(M1 - 1, y >> 1);
}

__global__ __launch_bounds__(256) void score_img_kernel(const float* __restrict__ sv_ws,
                                                        float* __restrict__ out) {
    int idx = blockIdx.x * 256 + threadIdx.x;
    if (idx >= OUT_SCORE_SZ) return;
    int x = idx & 127, y = (idx >> 7) & 127;
    int bk = idx >> 14;
    int r0, r1, s0, s1;
    oa_range(y, r0, r1);
    oa_range(x, s0, s1);
    const float* base = sv_ws + bk * NP;
    float acc = 0.f;
    for (int rr = r0; rr <= r1; rr++)
        for (int ss = s0; ss <= s1; ss++)
            acc += base[rr * M1 + ss];
    out[idx] = acc;
}

__global__ __launch_bounds__(256) void diff_img_kernel(const float* __restrict__ dsum_ws,
                                                       float* __restrict__ out) {
    int idx = blockIdx.x * 256 + threadIdx.x;
    if (idx >= OUT_DIFF_SZ) return;
    int x = idx & 127, y = (idx >> 7) & 127;
    int bkc = idx >> 14;
    int r0, r1, s0, s1;
    oa_range(y, r0, r1);
    oa_range(x, s0, s1);
    const float* base = dsum_ws + bkc * NP;
    float acc = 0.f;
    for (int rr = r0; rr <= r1; rr++)
        for (int ss = s0; ss <= s1; ss++)
            acc += base[rr * M1 + ss];
    out[idx] = acc;
}

extern "C" void kernel_launch(void* const* d_in, const int* in_sizes, int n_in,
                              void* d_out, int out_size, void* d_ws, size_t ws_size,
                              hipStream_t stream) {
    const float* xe = (const float*)d_in[0];
    const float* ye = (const float*)d_in[1];
    float* out = (float*)d_out;
    float* ws = (float*)d_ws;

    float* xnp = ws + WS_XNP;
    float* ynp = ws + WS_YNP;
    int*   topw = (int*)(ws + WS_TOP);
    float* sv_ws = ws + WS_SV;
    float* dsum_ws = ws + WS_DSUM;
    float* xpm = ws + WS_XPM;
    float* ypm = ws + WS_YPM;

    const bool pm_ok = (ws_size >= WS_NEED_BYTES);

    if (pm_ok) {
        im2patch_kernel<<<2 * B_ * M1, 256, 0, stream>>>(xe, ye, xpm, ypm);
    }
    norm_np_kernel<<<(2 * B_ * NP * 8 + 255) / 256, 256, 0, stream>>>(xe, ye, xnp, ynp);
    gemm_select_kernel<<<2 * 256, 1024, 0, stream>>>(xe, ye, xnp, topw);
    if (pm_ok) {
        emu_pm_kernel<<<B_ * NP, 256, 0, stream>>>(xpm, ypm, xnp, ynp, topw,
                                                   out + OUT_IDX_OFF, sv_ws, dsum_ws);
    } else {
        emu_fallback_kernel<<<B_ * NP, 256, 0, stream>>>(xe, ye, xnp, ynp, topw,
                                                         out + OUT_IDX_OFF, sv_ws, dsum_ws);
    }
    score_img_kernel<<<OUT_SCORE_SZ / 256, 256, 0, stream>>>(sv_ws, out);
    diff_img_kernel<<<OUT_DIFF_SZ / 256, 256, 0, stream>>>(dsum_ws, out + OUT_DIFF_OFF);
}

// Round 11
// 209.062 us; speedup vs baseline: 1.5426x; 1.1635x over previous
//
#include <hip/hip_runtime.h>
#include <float.h>
#include <math.h>

#define B_ 2
#define C_ 64
#define HW 64
#define M1 62
#define NP (M1*M1)      // 3844
#define WIN 30
#define KK 5
#define NSEL 16
#define HS 128

#define OUT_SCORE_SZ (B_*KK*HS*HS)       // 163840
#define OUT_IDX_OFF  (OUT_SCORE_SZ)
#define OUT_IDX_SZ   (B_*NP*KK)          // 38440
#define OUT_DIFF_OFF (OUT_IDX_OFF+OUT_IDX_SZ)
#define OUT_DIFF_SZ  (B_*KK*C_*HS*HS)    // 10485760

// ws layout in floats
#define WS_XNP 0                          // B_*NP = 7688 (pad 8192)
#define WS_YNP 8192
#define WS_TOP 16384                      // ints: B_*NP*16 = 123008
#define WS_SV  (16384+123008)             // 139392, B_*KK*NP = 38440 (pad 40960)
#define WS_DSUM (139392+40960)            // 180352, B_*KK*C_*NP = 2460160
#define WS_XPM  (180352+2460160)          // 2640512
#define XPM_F   (B_*NP*576)               // 4428288 floats
#define WS_YPM  (WS_XPM + XPM_F)          // 7068800
#define WS_NEED_BYTES ((size_t)(WS_YPM + XPM_F) * 4)   // ~46 MB

typedef __attribute__((ext_vector_type(8))) short bf16x8;
typedef __attribute__((ext_vector_type(4))) short bf16x4;
typedef __attribute__((ext_vector_type(4))) float f32x4;

__device__ __forceinline__ unsigned short f2bf(float f) {
    union { float f; unsigned int u; } v; v.f = f;
    unsigned int r = (v.u + 0x7FFFu + ((v.u >> 16) & 1u)) >> 16;
    return (unsigned short)r;
}

__device__ __forceinline__ bf16x8 ld_bf8(const short* p) {
    bf16x4 lo = *(const bf16x4*)p;
    bf16x4 hi = *(const bf16x4*)(p + 4);
    bf16x8 r;
    r[0] = lo[0]; r[1] = lo[1]; r[2] = lo[2]; r[3] = lo[3];
    r[4] = hi[0]; r[5] = hi[1]; r[6] = hi[2]; r[7] = hi[3];
    return r;
}

// ---------------- K0: im2patch (patch-major copies, e = c*9+p order) --------
__global__ __launch_bounds__(256) void im2patch_kernel(const float* __restrict__ xe,
                                                       const float* __restrict__ ye,
                                                       float* __restrict__ xpm,
                                                       float* __restrict__ ypm) {
    __shared__ float rows[3 * 64 * 64];
    __shared__ int tabL[576];
    const int tid = threadIdx.x;
    const int bid = blockIdx.x;
    const int srcI = bid / (B_ * 62);
    const int rem = bid - srcI * (B_ * 62);
    const int b = rem / M1, r = rem - b * M1;
    const float* src = (srcI ? ye : xe) + (size_t)b * C_ * HW * HW;
    float* dst = (srcI ? ypm : xpm) + (size_t)(b * NP + r * M1) * 576;

    for (int t = tid; t < 576; t += 256) {
        int c = t / 9, p = t - c * 9;
        tabL[t] = c * 192 + (p / 3) * 64 + (p % 3);
    }
    for (int i = tid; i < 64 * 192; i += 256) {
        rows[i] = src[(i / 192) * (HW * HW) + r * HW + (i % 192)];
    }
    __syncthreads();

    for (int s = 0; s < M1; s++) {
        float* d = dst + s * 576;
        for (int e = tid; e < 576; e += 256) d[e] = rows[tabL[e] + s];
    }
}

// ---------------- K1: numpy-pairwise norms (bitwise np emulation) ------------
__global__ __launch_bounds__(256) void norm_np_kernel(const float* __restrict__ xe,
                                                      const float* __restrict__ ye,
                                                      float* __restrict__ xnp,
                                                      float* __restrict__ ynp) {
    __shared__ int tab[576];
    for (int t = threadIdx.x; t < 576; t += 256) {
        int c = t / 9, p = t - c * 9;
        tab[t] = c * (HW * HW) + (p / 3) * HW + (p % 3);
    }
    __syncthreads();

    int gid = blockIdx.x * 256 + threadIdx.x;
    if (gid >= 2 * B_ * NP * 8) return;
    int which = gid / (B_ * NP * 8);
    int rem = gid - which * (B_ * NP * 8);
    int patch = rem >> 3, leaf = rem & 7;
    int b = patch / NP, m = patch - b * NP;
    int r = m / M1, s = m - r * M1;
    const float* src = (which ? ye : xe) + (size_t)b * C_ * HW * HW + r * HW + s;

    int base = leaf * 72;
    float a8[8];
    #pragma unroll
    for (int i = 0; i < 8; i++) {
        float v = src[tab[base + i]];
        a8[i] = v * v;
    }
    for (int i0 = 8; i0 < 72; i0 += 8) {
        #pragma unroll
        for (int i = 0; i < 8; i++) {
            float v = src[tab[base + i0 + i]];
            a8[i] += v * v;
        }
    }
    float t = ((a8[0] + a8[1]) + (a8[2] + a8[3])) + ((a8[4] + a8[5]) + (a8[6] + a8[7]));
    t = t + __shfl_xor(t, 1, 8);
    t = t + __shfl_xor(t, 2, 8);
    t = t + __shfl_xor(t, 4, 8);
    if (leaf == 0) (which ? ynp : xnp)[patch] = t;
}

// ---------------- K2: MFMA prescreen, 16-ch chunks, 2 blocks/CU -------------
#define UPC2 40
#define CSTR2 20                          // 16 ch + 4 pad shorts; 8B-granular
#define YSTR2 580                         // 4*144 + 4 pad; 8B-aligned per q
#define ZOFF_SH (16*YSTR2)                // zero block (16 shorts) in ys region
#define YS2_OFF 56000                     // bytes: xs = 35*40*20*2
#define XN2_OFF (YS2_OFF + (ZOFF_SH+16)*2)  // 74592
#define SM2_BYTES (XN2_OFF + 1089*4)        // 78948 -> 2 blocks/CU

__global__ __launch_bounds__(512, 4) void gemm_select_kernel(const float* __restrict__ xe,
                                                             const float* __restrict__ ye,
                                                             const float* __restrict__ ypm,
                                                             const float* __restrict__ xnp,
                                                             int* __restrict__ top_ws,
                                                             int use_pm) {
    __shared__ __align__(16) unsigned char smem[SM2_BYTES];
    short* xsS = (short*)smem;
    unsigned int* xsW = (unsigned int*)smem;
    short* ysS = (short*)(smem + YS2_OFF);
    float* xnL = (float*)(smem + XN2_OFF);
    float* Dl  = (float*)smem;            // overlays xs+ys after MFMA

    const int bid = blockIdx.x;
    const int b  = bid >> 8;
    const int t  = bid & 255;
    const int r0 = (t >> 4) * 4;
    const int s0 = (t & 15) * 4;
    const int u0r = min(max(r0 - 15, 0), 32);
    const int u0c = min(max(s0 - 15, 0), 32);
    const int g0c = min(u0c & ~3, 24);
    const int cofs = u0c - g0c;
    const int tid = threadIdx.x;
    const int l   = tid & 63;
    const int wid = tid >> 6;             // 0..7
    const int lq  = l & 15;
    const int kg  = l >> 4;
    const int kgh = kg >> 1, kgl = kg & 1;

    // --- stage y patches: layout ys[q][chunk(c>>4)][p][c&15] ---
    if (use_pm) {
        const float* ypb = ypm + (size_t)b * NP * 576;
        for (int u = tid; u < 16 * 576; u += 512) {
            int q = u / 576, e = u - q * 576;
            int rq = min(r0 + (q >> 2), 61), sq = min(s0 + (q & 3), 61);
            float v = ypb[(size_t)(rq * M1 + sq) * 576 + e];
            int c = e / 9, p = e - c * 9;
            ysS[q * YSTR2 + (c >> 4) * 144 + p * 16 + (c & 15)] = (short)f2bf(v);
        }
    } else {
        for (int u = tid; u < 16 * 576; u += 512) {
            int q = u / 576, e = u - q * 576;
            int rq = min(r0 + (q >> 2), 61), sq = min(s0 + (q & 3), 61);
            int c = e / 9, p = e - c * 9;
            float v = ye[((b * C_ + c) * HW + rq + p / 3) * HW + sq + p % 3];
            ysS[q * YSTR2 + (c >> 4) * 144 + p * 16 + (c & 15)] = (short)f2bf(v);
        }
    }
    if (tid < 16) ysS[ZOFF_SH + tid] = 0;
    for (int i = tid; i < 1089; i += 512) {
        int cr = i / 33, cc = i - cr * 33;
        int nr = min(u0r + cr, 61), nc = min(u0c + cc, 61);
        xnL[i] = xnp[b * NP + nr * M1 + nc];
    }

    f32x4 acc[10];
    #pragma unroll
    for (int i = 0; i < 10; i++) acc[i] = (f32x4){0.f, 0.f, 0.f, 0.f};

    // p-pair geometry: t: p0=2t, p1=2t+1 -> (pi,pj)
    const int PI0[4] = {0, 0, 1, 2}, PJ0[4] = {0, 2, 1, 0};
    const int PI1[4] = {0, 1, 1, 2}, PJ1[4] = {1, 0, 2, 1};

    for (int chunk = 0; chunk < 4; chunk++) {
        __syncthreads();
        // stage 16-ch chunk of 35x40 pixel union (8 ch-pairs)
        for (int u = tid; u < 560; u += 512) {
            int cp = u & 7, rh = u >> 3;           // rh 0..69
            int row = rh % 35, half = rh / 35;
            int c0 = chunk * 16 + cp * 2;
            int gr = min(u0r + row, 63);
            const float4* pa = (const float4*)(xe + ((size_t)(b * C_ + c0) * HW + gr) * HW + g0c);
            const float4* pb = (const float4*)(xe + ((size_t)(b * C_ + c0 + 1) * HW + gr) * HW + g0c);
            #pragma unroll
            for (int bb = 0; bb < 5; bb++) {
                int blk = half * 5 + bb;
                float4 va = pa[blk], vb = pb[blk];
                int w0 = (row * UPC2 + blk * 4) * (CSTR2 / 2) + cp;
                xsW[w0     ] = (unsigned)f2bf(va.x) | ((unsigned)f2bf(vb.x) << 16);
                xsW[w0 + 10] = (unsigned)f2bf(va.y) | ((unsigned)f2bf(vb.y) << 16);
                xsW[w0 + 20] = (unsigned)f2bf(va.z) | ((unsigned)f2bf(vb.z) << 16);
                xsW[w0 + 30] = (unsigned)f2bf(va.w) | ((unsigned)f2bf(vb.w) << 16);
            }
        }
        __syncthreads();

        // af fragments (A = queries), hoisted over candidate tiles
        const int aBase = lq * YSTR2 + chunk * 144;
        bf16x8 af[5];
        #pragma unroll
        for (int t4 = 0; t4 < 4; t4++) {
            int p = 2 * t4 + kgh;
            af[t4] = ld_bf8(ysS + aBase + p * 16 + kgl * 8);
        }
        af[4] = ld_bf8(ysS + ((kg < 2) ? (aBase + 8 * 16 + kgl * 8) : (ZOFF_SH + kgl * 8)));

        #pragma unroll
        for (int i = 0; i < 10; i++) {
            int ci = (wid * 10 + i) * 16 + lq;
            int cis = min(ci, 1088);
            int cr = cis / 33;
            int pr = cr, pc = cis - cr * 33 + cofs;
            #pragma unroll
            for (int t4 = 0; t4 < 4; t4++) {
                int pi = kgh ? PI1[t4] : PI0[t4];
                int pj = kgh ? PJ1[t4] : PJ0[t4];
                bf16x8 bf = ld_bf8(xsS + ((pr + pi) * UPC2 + (pc + pj)) * CSTR2 + kgl * 8);
                acc[i] = __builtin_amdgcn_mfma_f32_16x16x32_bf16(af[t4], bf, acc[i], 0, 0, 0);
            }
            {   // p = 8 (pi=2,pj=2), af upper half zero
                bf16x8 bf = ld_bf8(xsS + ((pr + 2) * UPC2 + (pc + 2)) * CSTR2 + kgl * 8);
                acc[i] = __builtin_amdgcn_mfma_f32_16x16x32_bf16(af[4], bf, acc[i], 0, 0, 0);
            }
        }
    }

    __syncthreads();
    // epilogue: D = xn - 2*dot; C layout col=lane&15(cand), row=(lane>>4)*4+j (query)
    #pragma unroll
    for (int i = 0; i < 10; i++) {
        int ci = (wid * 10 + i) * 16 + lq;
        if (ci < 1089) {
            float xnv = xnL[ci];
            #pragma unroll
            for (int j = 0; j < 4; j++) {
                Dl[(kg * 4 + j) * 1089 + ci] = xnv - 2.0f * acc[i][j];
            }
        }
    }
    __syncthreads();

    // packed-u32 top-16: key = (truncated sortable f32 << 10) | w
    for (int qq = 0; qq < 2; qq++) {
        int q = wid * 2 + qq;
        int rq = r0 + (q >> 2), sq = s0 + (q & 3);
        if (rq > 61 || sq > 61) continue;
        int siq = min(max(rq - 15, 0), 32);
        int sjq = min(max(sq - 15, 0), 32);
        int ro = siq - u0r, co = sjq - u0c;
        unsigned int kv[15];
        #pragma unroll
        for (int kk = 0; kk < 15; kk++) {
            int w = kk * 64 + l;
            if (w < 900) {
                int wi = w / 30, wj = w - wi * 30;
                float v = Dl[q * 1089 + (ro + wi) * 33 + (co + wj)];
                unsigned int u = __float_as_uint(v);
                u ^= (unsigned int)((int)u >> 31) | 0x80000000u;
                kv[kk] = (u & 0xFFFFFC00u) | (unsigned int)w;
            } else kv[kk] = 0xFFFFFFFFu;
        }
        int obase = (b * NP + rq * M1 + sq) * NSEL;
        for (int it = 0; it < NSEL; it++) {
            unsigned int lm = kv[0];
            #pragma unroll
            for (int kk = 1; kk < 15; kk++) lm = min(lm, kv[kk]);
            #pragma unroll
            for (int off = 32; off >= 1; off >>= 1)
                lm = min(lm, (unsigned int)__shfl_xor((int)lm, off));
            if (l == 0) {
                int w = (int)(lm & 1023u);
                int wi = w / 30, wj = w - wi * 30;
                top_ws[obase + it] = (siq + wi) * M1 + (sjq + wj);
            }
            #pragma unroll
            for (int kk = 0; kk < 15; kk++)
                if (kv[kk] == lm) kv[kk] = 0xFFFFFFFFu;
        }
    }
}

// ---------------- K3a: emu from patch-major buffers (dense reads) -----------
__global__ __launch_bounds__(256) void emu_pm_kernel(const float* __restrict__ xpm,
                                                     const float* __restrict__ ypm,
                                                     const float* __restrict__ xnp,
                                                     const float* __restrict__ ynp,
                                                     const int* __restrict__ top_ws,
                                                     float* __restrict__ out_idx,
                                                     float* __restrict__ sv_ws,
                                                     float* __restrict__ dsum_ws) {
    __shared__ float ysE[576];
    __shared__ int topWs[NSEL];
    __shared__ float keyEmu[NSEL];
    __shared__ float selKey[KK];
    __shared__ int   selN[KK];

    const int bid0 = blockIdx.x;
    const int bid = (bid0 & 7) * (B_ * NP / 8) + (bid0 >> 3);  // XCD-affine
    const int b = bid / NP, m = bid - b * NP;
    const int tid = threadIdx.x;
    const float* ybase = ypm + (size_t)(b * NP + m) * 576;

    for (int t = tid; t < 576; t += 256) ysE[t] = ybase[t];
    if (tid < NSEL) topWs[tid] = top_ws[bid * NSEL + tid];
    __syncthreads();

    {
        const int cand = tid >> 4, j = tid & 15;
        const float* xp = xpm + (size_t)(b * NP + topWs[cand]) * 576;
        float acc = 0.f;
        #pragma unroll
        for (int t = 0; t < 36; t++) {
            int e = t * 16 + j;
            acc = fmaf(ysE[e], xp[e], acc);
        }
        float E = acc;
        E = E + __shfl_xor(E, 8, 16);
        E = E + __shfl_xor(E, 4, 16);
        E = E + __shfl_xor(E, 2, 16);
        E = E + __shfl_xor(E, 1, 16);
        if (j == 0) {
            float t0 = -2.0f * E;
            float k1 = t0 + ynp[b * NP + m];
            float k2 = k1 + xnp[b * NP + topWs[cand]];
            keyEmu[cand] = k2 + 1e-5f;
        }
    }
    __syncthreads();

    if (tid == 0) {
        float d[NSEL]; int w[NSEL];
        for (int i = 0; i < NSEL; i++) { d[i] = keyEmu[i]; w[i] = topWs[i]; }
        for (int a = 1; a < NSEL; a++) {
            float dv = d[a]; int wv2 = w[a]; int p = a - 1;
            while (p >= 0 && (d[p] > dv || (d[p] == dv && w[p] > wv2))) {
                d[p + 1] = d[p]; w[p + 1] = w[p]; p--;
            }
            d[p + 1] = dv; w[p + 1] = wv2;
        }
        for (int i = 0; i < KK; i++) { selKey[i] = d[i]; selN[i] = w[i]; }
    }
    __syncthreads();

    if (tid < KK) {
        out_idx[(b * NP + m) * KK + tid] = (float)selN[tid];
        float s10 = selKey[tid] / 10.0f;
        double sv = exp(-(double)s10);
        sv_ws[(b * KK + tid) * NP + m] = (float)sv;
    }

    for (int pair = tid; pair < KK * C_; pair += 256) {
        int k = pair >> 6, c = pair & 63;
        const float* xrow = xpm + (size_t)(b * NP + selN[k]) * 576 + c * 9;
        const float* yrow = ysE + c * 9;
        float a = 0.f;
        #pragma unroll
        for (int p = 0; p < 9; p++) a += fabsf(yrow[p] - xrow[p]);
        dsum_ws[((b * KK + k) * C_ + c) * NP + m] = a;
    }
}

// ---------------- K3b: fallback emu (scattered) ------------------------------
#define XCSTR 584

__global__ __launch_bounds__(256) void emu_fallback_kernel(const float* __restrict__ xe,
                                                           const float* __restrict__ ye,
                                                           const float* __restrict__ xnp,
                                                           const float* __restrict__ ynp,
                                                           const int* __restrict__ top_ws,
                                                           float* __restrict__ out_idx,
                                                           float* __restrict__ sv_ws,
                                                           float* __restrict__ dsum_ws) {
    __shared__ float ysE[576];
    __shared__ int tab[576];
    __shared__ float xc[NSEL * XCSTR];
    __shared__ int topWs[NSEL];
    __shared__ float keyEmu[NSEL];
    __shared__ float selKey[KK];
    __shared__ int   selN[KK];
    __shared__ int   selI[KK];

    const int bid0 = blockIdx.x;
    const int bid = (bid0 & 7) * (B_ * NP / 8) + (bid0 >> 3);
    const int b = bid / NP, m = bid - b * NP;
    const int r = m / M1, s = m - r * M1;
    const int tid = threadIdx.x;
    const float* xb = xe + (size_t)b * C_ * HW * HW;
    const float* yb = ye + (size_t)b * C_ * HW * HW + r * HW + s;

    for (int t = tid; t < 576; t += 256) {
        int c = t / 9, p = t - c * 9;
        tab[t] = c * (HW * HW) + (p / 3) * HW + (p % 3);
    }
    if (tid < NSEL) topWs[tid] = top_ws[bid * NSEL + tid];
    __syncthreads();

    for (int t = tid; t < 576; t += 256) ysE[t] = yb[tab[t]];
    for (int i = tid; i < NSEL * 576; i += 256) {
        int cand = i / 576, e = i - cand * 576;
        int n = topWs[cand];
        int px = n / M1, py = n - px * M1;
        xc[cand * XCSTR + e] = xb[px * HW + py + tab[e]];
    }
    __syncthreads();

    {
        const int cand = tid >> 4, j = tid & 15;
        const float* xcp = xc + cand * XCSTR;
        float acc = 0.f;
        #pragma unroll
        for (int t = 0; t < 36; t++) {
            int e = t * 16 + j;
            acc = fmaf(ysE[e], xcp[e], acc);
        }
        float E = acc;
        E = E + __shfl_xor(E, 8, 16);
        E = E + __shfl_xor(E, 4, 16);
        E = E + __shfl_xor(E, 2, 16);
        E = E + __shfl_xor(E, 1, 16);
        if (j == 0) {
            float t0 = -2.0f * E;
            float k1 = t0 + ynp[b * NP + m];
            float k2 = k1 + xnp[b * NP + topWs[cand]];
            keyEmu[cand] = k2 + 1e-5f;
        }
    }
    __syncthreads();

    if (tid == 0) {
        float d[NSEL]; int w[NSEL]; int ix[NSEL];
        for (int i = 0; i < NSEL; i++) { d[i] = keyEmu[i]; w[i] = topWs[i]; ix[i] = i; }
        for (int a = 1; a < NSEL; a++) {
            float dv = d[a]; int wv2 = w[a]; int iv = ix[a]; int p = a - 1;
            while (p >= 0 && (d[p] > dv || (d[p] == dv && w[p] > wv2))) {
                d[p + 1] = d[p]; w[p + 1] = w[p]; ix[p + 1] = ix[p]; p--;
            }
            d[p + 1] = dv; w[p + 1] = wv2; ix[p + 1] = iv;
        }
        for (int i = 0; i < KK; i++) { selKey[i] = d[i]; selN[i] = w[i]; selI[i] = ix[i]; }
    }
    __syncthreads();

    if (tid < KK) {
        out_idx[(b * NP + m) * KK + tid] = (float)selN[tid];
        float s10 = selKey[tid] / 10.0f;
        double sv = exp(-(double)s10);
        sv_ws[(b * KK + tid) * NP + m] = (float)sv;
    }

    for (int pair = tid; pair < KK * C_; pair += 256) {
        int k = pair >> 6, c = pair & 63;
        const float* xcp = xc + selI[k] * XCSTR + c * 9;
        const float* ycp = ysE + c * 9;
        float a = 0.f;
        #pragma unroll
        for (int p = 0; p < 9; p++) a += fabsf(ycp[p] - xcp[p]);
        dsum_ws[((b * KK + k) * C_ + c) * NP + m] = a;
    }
}

// ---------------- overlap-add image kernels ---------------------------------
__device__ __forceinline__ void oa_range(int y, int& r0, int& r1) {
    r0 = (y >= 5) ? ((y - 4) >> 1) : 0;
    r1 = min(M1 - 1, y >> 1);
}

__global__ __launch_bounds__(256) void score_img_kernel(const float* __restrict__ sv_ws,
                                                        float* __restrict__ out) {
    int idx = blockIdx.x * 256 + threadIdx.x;
    if (idx >= OUT_SCORE_SZ) return;
    int x = idx & 127, y = (idx >> 7) & 127;
    int bk = idx >> 14;
    int r0, r1, s0, s1;
    oa_range(y, r0, r1);
    oa_range(x, s0, s1);
    const float* base = sv_ws + bk * NP;
    float acc = 0.f;
    for (int rr = r0; rr <= r1; rr++)
        for (int ss = s0; ss <= s1; ss++)
            acc += base[rr * M1 + ss];
    out[idx] = acc;
}

__global__ __launch_bounds__(256) void diff_img_kernel(const float* __restrict__ dsum_ws,
                                                       float* __restrict__ out) {
    int idx = blockIdx.x * 256 + threadIdx.x;
    if (idx >= OUT_DIFF_SZ) return;
    int x = idx & 127, y = (idx >> 7) & 127;
    int bkc = idx >> 14;
    int r0, r1, s0, s1;
    oa_range(y, r0, r1);
    oa_range(x, s0, s1);
    const float* base = dsum_ws + bkc * NP;
    float acc = 0.f;
    for (int rr = r0; rr <= r1; rr++)
        for (int ss = s0; ss <= s1; ss++)
            acc += base[rr * M1 + ss];
    out[idx] = acc;
}

extern "C" void kernel_launch(void* const* d_in, const int* in_sizes, int n_in,
                              void* d_out, int out_size, void* d_ws, size_t ws_size,
                              hipStream_t stream) {
    const float* xe = (const float*)d_in[0];
    const float* ye = (const float*)d_in[1];
    float* out = (float*)d_out;
    float* ws = (float*)d_ws;

    float* xnp = ws + WS_XNP;
    float* ynp = ws + WS_YNP;
    int*   topw = (int*)(ws + WS_TOP);
    float* sv_ws = ws + WS_SV;
    float* dsum_ws = ws + WS_DSUM;
    float* xpm = ws + WS_XPM;
    float* ypm = ws + WS_YPM;

    const bool pm_ok = (ws_size >= WS_NEED_BYTES);

    if (pm_ok) {
        im2patch_kernel<<<2 * B_ * M1, 256, 0, stream>>>(xe, ye, xpm, ypm);
    }
    norm_np_kernel<<<(2 * B_ * NP * 8 + 255) / 256, 256, 0, stream>>>(xe, ye, xnp, ynp);
    gemm_select_kernel<<<2 * 256, 512, 0, stream>>>(xe, ye, pm_ok ? ypm : (const float*)nullptr,
                                                    xnp, topw, pm_ok ? 1 : 0);
    if (pm_ok) {
        emu_pm_kernel<<<B_ * NP, 256, 0, stream>>>(xpm, ypm, xnp, ynp, topw,
                                                   out + OUT_IDX_OFF, sv_ws, dsum_ws);
    } else {
        emu_fallback_kernel<<<B_ * NP, 256, 0, stream>>>(xe, ye, xnp, ynp, topw,
                                                         out + OUT_IDX_OFF, sv_ws, dsum_ws);
    }
    score_img_kernel<<<OUT_SCORE_SZ / 256, 256, 0, stream>>>(sv_ws, out);
    diff_img_kernel<<<OUT_DIFF_SZ / 256, 256, 0, stream>>>(dsum_ws, out + OUT_DIFF_OFF);
}

// Round 12
// 203.162 us; speedup vs baseline: 1.5874x; 1.0290x over previous
//
#include <hip/hip_runtime.h>
#include <float.h>
#include <math.h>

#define B_ 2
#define C_ 64
#define HW 64
#define M1 62
#define NP (M1*M1)      // 3844
#define WIN 30
#define KK 5
#define NSEL 16
#define HS 128

#define OUT_SCORE_SZ (B_*KK*HS*HS)       // 163840
#define OUT_IDX_OFF  (OUT_SCORE_SZ)
#define OUT_IDX_SZ   (B_*NP*KK)          // 38440
#define OUT_DIFF_OFF (OUT_IDX_OFF+OUT_IDX_SZ)
#define OUT_DIFF_SZ  (B_*KK*C_*HS*HS)    // 10485760

// ws layout in floats
#define WS_XNP 0                          // B_*NP = 7688 (pad 8192)
#define WS_YNP 8192
#define WS_TOP 16384                      // ints: B_*NP*16 = 123008
#define WS_SV  (16384+123008)             // 139392, B_*KK*NP = 38440 (pad 40960)
#define WS_DSUM (139392+40960)            // 180352, B_*KK*C_*NP = 2460160
#define WS_XPM  (180352+2460160)          // 2640512
#define XPM_F   (B_*NP*576)               // 4428288 floats
#define WS_YPM  (WS_XPM + XPM_F)          // 7068800
#define WS_NEED_BYTES ((size_t)(WS_YPM + XPM_F) * 4)   // ~46 MB

typedef __attribute__((ext_vector_type(8))) short bf16x8;
typedef __attribute__((ext_vector_type(4))) short bf16x4;
typedef __attribute__((ext_vector_type(4))) float f32x4;

__device__ __forceinline__ unsigned short f2bf(float f) {
    union { float f; unsigned int u; } v; v.f = f;
    unsigned int r = (v.u + 0x7FFFu + ((v.u >> 16) & 1u)) >> 16;
    return (unsigned short)r;
}

__device__ __forceinline__ bf16x8 ld_bf8(const short* p) {
    bf16x4 lo = *(const bf16x4*)p;
    bf16x4 hi = *(const bf16x4*)(p + 4);
    bf16x8 r;
    r[0] = lo[0]; r[1] = lo[1]; r[2] = lo[2]; r[3] = lo[3];
    r[4] = hi[0]; r[5] = hi[1]; r[6] = hi[2]; r[7] = hi[3];
    return r;
}

// ---------------- K0: im2patch (patch-major copies, e = c*9+p order) --------
__global__ __launch_bounds__(256) void im2patch_kernel(const float* __restrict__ xe,
                                                       const float* __restrict__ ye,
                                                       float* __restrict__ xpm,
                                                       float* __restrict__ ypm) {
    __shared__ float rows[3 * 64 * 64];
    __shared__ int tabL[576];
    const int tid = threadIdx.x;
    const int bid = blockIdx.x;
    const int srcI = bid / (B_ * 62);
    const int rem = bid - srcI * (B_ * 62);
    const int b = rem / M1, r = rem - b * M1;
    const float* src = (srcI ? ye : xe) + (size_t)b * C_ * HW * HW;
    float* dst = (srcI ? ypm : xpm) + (size_t)(b * NP + r * M1) * 576;

    for (int t = tid; t < 576; t += 256) {
        int c = t / 9, p = t - c * 9;
        tabL[t] = c * 192 + (p / 3) * 64 + (p % 3);
    }
    for (int i = tid; i < 64 * 192; i += 256) {
        rows[i] = src[(i / 192) * (HW * HW) + r * HW + (i % 192)];
    }
    __syncthreads();

    for (int s = 0; s < M1; s++) {
        float* d = dst + s * 576;
        for (int e = tid; e < 576; e += 256) d[e] = rows[tabL[e] + s];
    }
}

// ---------------- K1: numpy-pairwise norms (bitwise np emulation) ------------
__global__ __launch_bounds__(256) void norm_np_kernel(const float* __restrict__ xe,
                                                      const float* __restrict__ ye,
                                                      float* __restrict__ xnp,
                                                      float* __restrict__ ynp) {
    __shared__ int tab[576];
    for (int t = threadIdx.x; t < 576; t += 256) {
        int c = t / 9, p = t - c * 9;
        tab[t] = c * (HW * HW) + (p / 3) * HW + (p % 3);
    }
    __syncthreads();

    int gid = blockIdx.x * 256 + threadIdx.x;
    if (gid >= 2 * B_ * NP * 8) return;
    int which = gid / (B_ * NP * 8);
    int rem = gid - which * (B_ * NP * 8);
    int patch = rem >> 3, leaf = rem & 7;
    int b = patch / NP, m = patch - b * NP;
    int r = m / M1, s = m - r * M1;
    const float* src = (which ? ye : xe) + (size_t)b * C_ * HW * HW + r * HW + s;

    int base = leaf * 72;
    float a8[8];
    #pragma unroll
    for (int i = 0; i < 8; i++) {
        float v = src[tab[base + i]];
        a8[i] = v * v;
    }
    for (int i0 = 8; i0 < 72; i0 += 8) {
        #pragma unroll
        for (int i = 0; i < 8; i++) {
            float v = src[tab[base + i0 + i]];
            a8[i] += v * v;
        }
    }
    float t = ((a8[0] + a8[1]) + (a8[2] + a8[3])) + ((a8[4] + a8[5]) + (a8[6] + a8[7]));
    t = t + __shfl_xor(t, 1, 8);
    t = t + __shfl_xor(t, 2, 8);
    t = t + __shfl_xor(t, 4, 8);
    if (leaf == 0) (which ? ynp : xnp)[patch] = t;
}

// ---------------- K2: MFMA prescreen, 16-ch chunks, 2 blocks/CU -------------
#define UPC2 40
#define CSTR2 20                          // 16 ch + 4 pad shorts; 8B-granular
#define YSTR2 580                         // 4*144 + 4 pad
#define ZOFF_SH (16*YSTR2)                // zero block in ys region
#define YS2_OFF 56000                     // bytes: xs = 35*40*20*2
#define XN2_OFF (YS2_OFF + (ZOFF_SH+16)*2)  // 74592
#define SM2_BYTES (XN2_OFF + 1089*4)        // 78948 -> 2 blocks/CU

__global__ __launch_bounds__(512, 4) void gemm_select_kernel(const float* __restrict__ xe,
                                                             const float* __restrict__ ye,
                                                             const float* __restrict__ ypm,
                                                             const float* __restrict__ xnp,
                                                             int* __restrict__ top_ws,
                                                             int use_pm) {
    __shared__ __align__(16) unsigned char smem[SM2_BYTES];
    short* xsS = (short*)smem;
    unsigned int* xsW = (unsigned int*)smem;
    short* ysS = (short*)(smem + YS2_OFF);
    float* xnL = (float*)(smem + XN2_OFF);
    float* Dl  = (float*)smem;            // overlays xs+ys after MFMA

    const int bid = blockIdx.x;
    const int b  = bid >> 8;
    const int t  = bid & 255;
    const int r0 = (t >> 4) * 4;
    const int s0 = (t & 15) * 4;
    const int u0r = min(max(r0 - 15, 0), 32);
    const int u0c = min(max(s0 - 15, 0), 32);
    const int g0c = min(u0c & ~3, 24);
    const int cofs = u0c - g0c;
    const int tid = threadIdx.x;
    const int l   = tid & 63;
    const int wid = tid >> 6;             // 0..7
    const int lq  = l & 15;
    const int kg  = l >> 4;
    const int kgh = kg >> 1, kgl = kg & 1;

    // --- stage y patches: layout ys[q][chunk(c>>4)][p][c&15] ---
    if (use_pm) {
        const float* ypb = ypm + (size_t)b * NP * 576;
        for (int u = tid; u < 16 * 576; u += 512) {
            int q = u / 576, e = u - q * 576;
            int rq = min(r0 + (q >> 2), 61), sq = min(s0 + (q & 3), 61);
            float v = ypb[(size_t)(rq * M1 + sq) * 576 + e];
            int c = e / 9, p = e - c * 9;
            ysS[q * YSTR2 + (c >> 4) * 144 + p * 16 + (c & 15)] = (short)f2bf(v);
        }
    } else {
        for (int u = tid; u < 16 * 576; u += 512) {
            int q = u / 576, e = u - q * 576;
            int rq = min(r0 + (q >> 2), 61), sq = min(s0 + (q & 3), 61);
            int c = e / 9, p = e - c * 9;
            float v = ye[((b * C_ + c) * HW + rq + p / 3) * HW + sq + p % 3];
            ysS[q * YSTR2 + (c >> 4) * 144 + p * 16 + (c & 15)] = (short)f2bf(v);
        }
    }
    if (tid < 16) ysS[ZOFF_SH + tid] = 0;
    for (int i = tid; i < 1089; i += 512) {
        int cr = i / 33, cc = i - cr * 33;
        int nr = min(u0r + cr, 61), nc = min(u0c + cc, 61);
        xnL[i] = xnp[b * NP + nr * M1 + nc];
    }

    f32x4 acc[10];
    #pragma unroll
    for (int i = 0; i < 10; i++) acc[i] = (f32x4){0.f, 0.f, 0.f, 0.f};

    // p-pair geometry: t4: p0=2t4, p1=2t4+1 -> (pi,pj)
    const int PI0[4] = {0, 0, 1, 2}, PJ0[4] = {0, 2, 1, 0};
    const int PI1[4] = {0, 1, 1, 2}, PJ1[4] = {1, 0, 2, 1};

    int prb[10], pcb[10];
    #pragma unroll
    for (int i = 0; i < 10; i++) {
        int ci = (wid * 10 + i) * 16 + lq;
        int cis = min(ci, 1088);
        int cr = cis / 33;
        prb[i] = cr;
        pcb[i] = cis - cr * 33 + cofs;
    }

    for (int chunk = 0; chunk < 4; chunk++) {
        __syncthreads();
        // stage 16-ch chunk of 35x40 pixel union (8 ch-pairs)
        for (int u = tid; u < 560; u += 512) {
            int cp = u & 7, rh = u >> 3;
            int row = rh % 35, half = rh / 35;
            int c0 = chunk * 16 + cp * 2;
            int gr = min(u0r + row, 63);
            const float4* pa = (const float4*)(xe + ((size_t)(b * C_ + c0) * HW + gr) * HW + g0c);
            const float4* pb = (const float4*)(xe + ((size_t)(b * C_ + c0 + 1) * HW + gr) * HW + g0c);
            #pragma unroll
            for (int bb = 0; bb < 5; bb++) {
                int blk = half * 5 + bb;
                float4 va = pa[blk], vb = pb[blk];
                int w0 = (row * UPC2 + blk * 4) * (CSTR2 / 2) + cp;
                xsW[w0     ] = (unsigned)f2bf(va.x) | ((unsigned)f2bf(vb.x) << 16);
                xsW[w0 + 10] = (unsigned)f2bf(va.y) | ((unsigned)f2bf(vb.y) << 16);
                xsW[w0 + 20] = (unsigned)f2bf(va.z) | ((unsigned)f2bf(vb.z) << 16);
                xsW[w0 + 30] = (unsigned)f2bf(va.w) | ((unsigned)f2bf(vb.w) << 16);
            }
        }
        __syncthreads();

        // t4 OUTER / candidate-tile INNER: one af live at a time (no spill).
        // Per-acc[i] accumulation order is t4 = 0..4 ascending, identical to
        // the previous i-outer/t4-inner form -> bitwise-same prescreen keys.
        const int aBase = lq * YSTR2 + chunk * 144;
        #pragma unroll
        for (int t4 = 0; t4 < 5; t4++) {
            bf16x8 af;
            int pi, pj;
            if (t4 < 4) {
                int p = 2 * t4 + kgh;
                af = ld_bf8(ysS + aBase + p * 16 + kgl * 8);
                pi = kgh ? PI1[t4] : PI0[t4];
                pj = kgh ? PJ1[t4] : PJ0[t4];
            } else {   // p = 8 (pi=2,pj=2); upper K-half zero for kg>=2
                af = ld_bf8(ysS + ((kg < 2) ? (aBase + 8 * 16 + kgl * 8) : (ZOFF_SH + kgl * 8)));
                pi = 2; pj = 2;
            }
            #pragma unroll
            for (int i = 0; i < 10; i++) {
                bf16x8 bf = ld_bf8(xsS + ((prb[i] + pi) * UPC2 + (pcb[i] + pj)) * CSTR2 + kgl * 8);
                acc[i] = __builtin_amdgcn_mfma_f32_16x16x32_bf16(af, bf, acc[i], 0, 0, 0);
            }
        }
    }

    __syncthreads();
    // epilogue: D = xn - 2*dot; C layout col=lane&15(cand), row=(lane>>4)*4+j (query)
    #pragma unroll
    for (int i = 0; i < 10; i++) {
        int ci = (wid * 10 + i) * 16 + lq;
        if (ci < 1089) {
            float xnv = xnL[ci];
            #pragma unroll
            for (int j = 0; j < 4; j++) {
                Dl[(kg * 4 + j) * 1089 + ci] = xnv - 2.0f * acc[i][j];
            }
        }
    }
    __syncthreads();

    // packed-u32 top-16: key = (truncated sortable f32 << 10) | w
    for (int qq = 0; qq < 2; qq++) {
        int q = wid * 2 + qq;
        int rq = r0 + (q >> 2), sq = s0 + (q & 3);
        if (rq > 61 || sq > 61) continue;
        int siq = min(max(rq - 15, 0), 32);
        int sjq = min(max(sq - 15, 0), 32);
        int ro = siq - u0r, co = sjq - u0c;
        unsigned int kv[15];
        #pragma unroll
        for (int kk = 0; kk < 15; kk++) {
            int w = kk * 64 + l;
            if (w < 900) {
                int wi = w / 30, wj = w - wi * 30;
                float v = Dl[q * 1089 + (ro + wi) * 33 + (co + wj)];
                unsigned int u = __float_as_uint(v);
                u ^= (unsigned int)((int)u >> 31) | 0x80000000u;
                kv[kk] = (u & 0xFFFFFC00u) | (unsigned int)w;
            } else kv[kk] = 0xFFFFFFFFu;
        }
        int obase = (b * NP + rq * M1 + sq) * NSEL;
        for (int it = 0; it < NSEL; it++) {
            unsigned int lm = kv[0];
            #pragma unroll
            for (int kk = 1; kk < 15; kk++) lm = min(lm, kv[kk]);
            #pragma unroll
            for (int off = 32; off >= 1; off >>= 1)
                lm = min(lm, (unsigned int)__shfl_xor((int)lm, off));
            if (l == 0) {
                int w = (int)(lm & 1023u);
                int wi = w / 30, wj = w - wi * 30;
                top_ws[obase + it] = (siq + wi) * M1 + (sjq + wj);
            }
            #pragma unroll
            for (int kk = 0; kk < 15; kk++)
                if (kv[kk] == lm) kv[kk] = 0xFFFFFFFFu;
        }
    }
}

// ---------------- K3a: emu from patch-major buffers (dense reads) -----------
__global__ __launch_bounds__(256) void emu_pm_kernel(const float* __restrict__ xpm,
                                                     const float* __restrict__ ypm,
                                                     const float* __restrict__ xnp,
                                                     const float* __restrict__ ynp,
                                                     const int* __restrict__ top_ws,
                                                     float* __restrict__ out_idx,
                                                     float* __restrict__ sv_ws,
                                                     float* __restrict__ dsum_ws) {
    __shared__ float ysE[576];
    __shared__ int topWs[NSEL];
    __shared__ float keyEmu[NSEL];
    __shared__ float selKey[KK];
    __shared__ int   selN[KK];

    const int bid0 = blockIdx.x;
    const int bid = (bid0 & 7) * (B_ * NP / 8) + (bid0 >> 3);  // XCD-affine
    const int b = bid / NP, m = bid - b * NP;
    const int tid = threadIdx.x;
    const float* ybase = ypm + (size_t)(b * NP + m) * 576;

    for (int t = tid; t < 576; t += 256) ysE[t] = ybase[t];
    if (tid < NSEL) topWs[tid] = top_ws[bid * NSEL + tid];
    __syncthreads();

    {
        const int cand = tid >> 4, j = tid & 15;
        const float* xp = xpm + (size_t)(b * NP + topWs[cand]) * 576;
        float acc = 0.f;
        #pragma unroll
        for (int t = 0; t < 36; t++) {
            int e = t * 16 + j;
            acc = fmaf(ysE[e], xp[e], acc);
        }
        float E = acc;
        E = E + __shfl_xor(E, 8, 16);
        E = E + __shfl_xor(E, 4, 16);
        E = E + __shfl_xor(E, 2, 16);
        E = E + __shfl_xor(E, 1, 16);
        if (j == 0) {
            float t0 = -2.0f * E;
            float k1 = t0 + ynp[b * NP + m];
            float k2 = k1 + xnp[b * NP + topWs[cand]];
            keyEmu[cand] = k2 + 1e-5f;
        }
    }
    __syncthreads();

    if (tid == 0) {
        float d[NSEL]; int w[NSEL];
        for (int i = 0; i < NSEL; i++) { d[i] = keyEmu[i]; w[i] = topWs[i]; }
        for (int a = 1; a < NSEL; a++) {
            float dv = d[a]; int wv2 = w[a]; int p = a - 1;
            while (p >= 0 && (d[p] > dv || (d[p] == dv && w[p] > wv2))) {
                d[p + 1] = d[p]; w[p + 1] = w[p]; p--;
            }
            d[p + 1] = dv; w[p + 1] = wv2;
        }
        for (int i = 0; i < KK; i++) { selKey[i] = d[i]; selN[i] = w[i]; }
    }
    __syncthreads();

    if (tid < KK) {
        out_idx[(b * NP + m) * KK + tid] = (float)selN[tid];
        float s10 = selKey[tid] / 10.0f;
        double sv = exp(-(double)s10);
        sv_ws[(b * KK + tid) * NP + m] = (float)sv;
    }

    for (int pair = tid; pair < KK * C_; pair += 256) {
        int k = pair >> 6, c = pair & 63;
        const float* xrow = xpm + (size_t)(b * NP + selN[k]) * 576 + c * 9;
        const float* yrow = ysE + c * 9;
        float a = 0.f;
        #pragma unroll
        for (int p = 0; p < 9; p++) a += fabsf(yrow[p] - xrow[p]);
        dsum_ws[((b * KK + k) * C_ + c) * NP + m] = a;
    }
}

// ---------------- K3b: fallback emu (scattered) ------------------------------
#define XCSTR 584

__global__ __launch_bounds__(256) void emu_fallback_kernel(const float* __restrict__ xe,
                                                           const float* __restrict__ ye,
                                                           const float* __restrict__ xnp,
                                                           const float* __restrict__ ynp,
                                                           const int* __restrict__ top_ws,
                                                           float* __restrict__ out_idx,
                                                           float* __restrict__ sv_ws,
                                                           float* __restrict__ dsum_ws) {
    __shared__ float ysE[576];
    __shared__ int tab[576];
    __shared__ float xc[NSEL * XCSTR];
    __shared__ int topWs[NSEL];
    __shared__ float keyEmu[NSEL];
    __shared__ float selKey[KK];
    __shared__ int   selN[KK];
    __shared__ int   selI[KK];

    const int bid0 = blockIdx.x;
    const int bid = (bid0 & 7) * (B_ * NP / 8) + (bid0 >> 3);
    const int b = bid / NP, m = bid - b * NP;
    const int r = m / M1, s = m - r * M1;
    const int tid = threadIdx.x;
    const float* xb = xe + (size_t)b * C_ * HW * HW;
    const float* yb = ye + (size_t)b * C_ * HW * HW + r * HW + s;

    for (int t = tid; t < 576; t += 256) {
        int c = t / 9, p = t - c * 9;
        tab[t] = c * (HW * HW) + (p / 3) * HW + (p % 3);
    }
    if (tid < NSEL) topWs[tid] = top_ws[bid * NSEL + tid];
    __syncthreads();

    for (int t = tid; t < 576; t += 256) ysE[t] = yb[tab[t]];
    for (int i = tid; i < NSEL * 576; i += 256) {
        int cand = i / 576, e = i - cand * 576;
        int n = topWs[cand];
        int px = n / M1, py = n - px * M1;
        xc[cand * XCSTR + e] = xb[px * HW + py + tab[e]];
    }
    __syncthreads();

    {
        const int cand = tid >> 4, j = tid & 15;
        const float* xcp = xc + cand * XCSTR;
        float acc = 0.f;
        #pragma unroll
        for (int t = 0; t < 36; t++) {
            int e = t * 16 + j;
            acc = fmaf(ysE[e], xcp[e], acc);
        }
        float E = acc;
        E = E + __shfl_xor(E, 8, 16);
        E = E + __shfl_xor(E, 4, 16);
        E = E + __shfl_xor(E, 2, 16);
        E = E + __shfl_xor(E, 1, 16);
        if (j == 0) {
            float t0 = -2.0f * E;
            float k1 = t0 + ynp[b * NP + m];
            float k2 = k1 + xnp[b * NP + topWs[cand]];
            keyEmu[cand] = k2 + 1e-5f;
        }
    }
    __syncthreads();

    if (tid == 0) {
        float d[NSEL]; int w[NSEL]; int ix[NSEL];
        for (int i = 0; i < NSEL; i++) { d[i] = keyEmu[i]; w[i] = topWs[i]; ix[i] = i; }
        for (int a = 1; a < NSEL; a++) {
            float dv = d[a]; int wv2 = w[a]; int iv = ix[a]; int p = a - 1;
            while (p >= 0 && (d[p] > dv || (d[p] == dv && w[p] > wv2))) {
                d[p + 1] = d[p]; w[p + 1] = w[p]; ix[p + 1] = ix[p]; p--;
            }
            d[p + 1] = dv; w[p + 1] = wv2; ix[p + 1] = iv;
        }
        for (int i = 0; i < KK; i++) { selKey[i] = d[i]; selN[i] = w[i]; selI[i] = ix[i]; }
    }
    __syncthreads();

    if (tid < KK) {
        out_idx[(b * NP + m) * KK + tid] = (float)selN[tid];
        float s10 = selKey[tid] / 10.0f;
        double sv = exp(-(double)s10);
        sv_ws[(b * KK + tid) * NP + m] = (float)sv;
    }

    for (int pair = tid; pair < KK * C_; pair += 256) {
        int k = pair >> 6, c = pair & 63;
        const float* xcp = xc + selI[k] * XCSTR + c * 9;
        const float* ycp = ysE + c * 9;
        float a = 0.f;
        #pragma unroll
        for (int p = 0; p < 9; p++) a += fabsf(ycp[p] - xcp[p]);
        dsum_ws[((b * KK + k) * C_ + c) * NP + m] = a;
    }
}

// ---------------- overlap-add image kernels ---------------------------------
__device__ __forceinline__ void oa_range(int y, int& r0, int& r1) {
    r0 = (y >= 5) ? ((y - 4) >> 1) : 0;
    r1 = min(M1 - 1, y >> 1);
}

__global__ __launch_bounds__(256) void score_img_kernel(const float* __restrict__ sv_ws,
                                                        float* __restrict__ out) {
    int idx = blockIdx.x * 256 + threadIdx.x;
    if (idx >= OUT_SCORE_SZ) return;
    int x = idx & 127, y = (idx >> 7) & 127;
    int bk = idx >> 14;
    int r0, r1, s0, s1;
    oa_range(y, r0, r1);
    oa_range(x, s0, s1);
    const float* base = sv_ws + bk * NP;
    float acc = 0.f;
    for (int rr = r0; rr <= r1; rr++)
        for (int ss = s0; ss <= s1; ss++)
            acc += base[rr * M1 + ss];
    out[idx] = acc;
}

__global__ __launch_bounds__(256) void diff_img_kernel(const float* __restrict__ dsum_ws,
                                                       float* __restrict__ out) {
    int idx = blockIdx.x * 256 + threadIdx.x;
    if (idx >= OUT_DIFF_SZ) return;
    int x = idx & 127, y = (idx >> 7) & 127;
    int bkc = idx >> 14;
    int r0, r1, s0, s1;
    oa_range(y, r0, r1);
    oa_range(x, s0, s1);
    const float* base = dsum_ws + bkc * NP;
    float acc = 0.f;
    for (int rr = r0; rr <= r1; rr++)
        for (int ss = s0; ss <= s1; ss++)
            acc += base[rr * M1 + ss];
    out[idx] = acc;
}

extern "C" void kernel_launch(void* const* d_in, const int* in_sizes, int n_in,
                              void* d_out, int out_size, void* d_ws, size_t ws_size,
                              hipStream_t stream) {
    const float* xe = (const float*)d_in[0];
    const float* ye = (const float*)d_in[1];
    float* out = (float*)d_out;
    float* ws = (float*)d_ws;

    float* xnp = ws + WS_XNP;
    float* ynp = ws + WS_YNP;
    int*   topw = (int*)(ws + WS_TOP);
    float* sv_ws = ws + WS_SV;
    float* dsum_ws = ws + WS_DSUM;
    float* xpm = ws + WS_XPM;
    float* ypm = ws + WS_YPM;

    const bool pm_ok = (ws_size >= WS_NEED_BYTES);

    if (pm_ok) {
        im2patch_kernel<<<2 * B_ * M1, 256, 0, stream>>>(xe, ye, xpm, ypm);
    }
    norm_np_kernel<<<(2 * B_ * NP * 8 + 255) / 256, 256, 0, stream>>>(xe, ye, xnp, ynp);
    gemm_select_kernel<<<2 * 256, 512, 0, stream>>>(xe, ye, pm_ok ? ypm : (const float*)nullptr,
                                                    xnp, topw, pm_ok ? 1 : 0);
    if (pm_ok) {
        emu_pm_kernel<<<B_ * NP, 256, 0, stream>>>(xpm, ypm, xnp, ynp, topw,
                                                   out + OUT_IDX_OFF, sv_ws, dsum_ws);
    } else {
        emu_fallback_kernel<<<B_ * NP, 256, 0, stream>>>(xe, ye, xnp, ynp, topw,
                                                         out + OUT_IDX_OFF, sv_ws, dsum_ws);
    }
    score_img_kernel<<<OUT_SCORE_SZ / 256, 256, 0, stream>>>(sv_ws, out);
    diff_img_kernel<<<OUT_DIFF_SZ / 256, 256, 0, stream>>>(dsum_ws, out + OUT_DIFF_OFF);
}